// Round 2
// baseline (525.369 us; speedup 1.0000x reference)
//
#include <hip/hip_runtime.h>
#include <stdint.h>

// Fused LN1 -> Linear(1024->256) -> LN2, single pass over X.
//   LN1 folded into epilogue: y = rs*(X @ (W*g1)^T - mu*s1) + s2
//     s1[p] = sum_k g1[k]W[p,k], s2[p] = sum_k b1[k]W[p,k] + b[p]   (prep)
//   3-MFMA split precision: Wg = Wh + Wl (bf16 pair), x = xh + xl (bf16 pair)
//     acc += xh*Wh + xl*Wh + xh*Wl   (drop xl*Wl ~ 2^-18)
//   Wh staged via global_load_lds from a PRE-SWIZZLED chunk-major layout
//     (rule #21: linear LDS dest + inverse-swizzled source + swizzled read)
//     swizzle: k-group g -> g ^ ((p>>1)&3)  => B-frag ds_read_b128 is 2-way (free)
//   Wl fragments register-prefetched per-wave from global (L1/L2-resident).

#define D_MODEL 1024
#define D_PROJ  256
#define BM      64
#define BK      32
#define KITERS  32
#define NTHR    512
#define XSTR    40      // xh/xl row stride (elems) = 80 B -> 2-way (free) b128 reads
#define EPS     1e-5f

typedef __attribute__((ext_vector_type(4))) float  f32x4;
typedef __attribute__((ext_vector_type(8))) __bf16 bf16x8;

__device__ __forceinline__ void gll16(const void* g, void* l) {
  __builtin_amdgcn_global_load_lds(
      (const __attribute__((address_space(1))) uint32_t*)g,
      (__attribute__((address_space(3))) uint32_t*)l, 16, 0, 0);
}

// ---------------- prep: Wg = W*g1 -> (Wh swizzled chunk-major, Wl plain), s1, s2 ----------------
__global__ __launch_bounds__(256) void prep_kernel(
    const float* __restrict__ W, const float* __restrict__ g1,
    const float* __restrict__ b1, const float* __restrict__ bias,
    __bf16* __restrict__ wh, __bf16* __restrict__ wl,
    float* __restrict__ s1, float* __restrict__ s2) {
  const int p = blockIdx.x;
  const int t = threadIdx.x;                 // owns k = 4t..4t+3
  f32x4 w4  = *(const f32x4*)(W  + (size_t)p * D_MODEL + t * 4);
  f32x4 g4  = *(const f32x4*)(g1 + t * 4);
  f32x4 b14 = *(const f32x4*)(b1 + t * 4);
  union { __bf16 h[4]; uint64_t u; } ph, pl;
  float a = 0.f, c = 0.f;
#pragma unroll
  for (int j = 0; j < 4; ++j) {
    float wg = w4[j] * g4[j];
    a += wg;
    c += b14[j] * w4[j];
    __bf16 hb = (__bf16)wg;
    ph.h[j] = hb;
    pl.h[j] = (__bf16)(wg - (float)hb);
  }
  // wh: chunk-major [c][p][swizzled 32 elems]; k=4t -> c=t>>3, g=(t>>1)&3, e0=(t&1)*4
  const int cc = t >> 3, g = (t >> 1) & 3, e0 = (t & 1) * 4;
  const int swz = g ^ ((p >> 1) & 3);
  *(uint64_t*)(wh + (size_t)cc * 8192 + p * 32 + swz * 8 + e0) = ph.u;
  *(uint64_t*)(wl + (size_t)p * D_MODEL + t * 4) = pl.u;   // plain row-major
#pragma unroll
  for (int m = 1; m < 64; m <<= 1) {
    a += __shfl_xor(a, m, 64);
    c += __shfl_xor(c, m, 64);
  }
  __shared__ float ra[4], rc[4];
  if ((t & 63) == 0) { ra[t >> 6] = a; rc[t >> 6] = c; }
  __syncthreads();
  if (t == 0) {
    s1[p] = ra[0] + ra[1] + ra[2] + ra[3];
    s2[p] = rc[0] + rc[1] + rc[2] + rc[3] + bias[p];
  }
}

// ---------------- fused main ----------------
struct __align__(16) LdsT {
  __bf16 w[2][D_PROJ * BK];     // Wh double-buffer, swizzled chunk image, 2 x 16 KB
  __bf16 xh[BM * XSTR];         // 5120 B
  __bf16 xl[BM * XSTR];         // 5120 B
  float  mu[BM], rs[BM];
  float  red_s[4][BM], red_q[4][BM];
};                              // 45,568 B -> <64 KB static; 2 blocks/CU (reg-capped)

__global__ __launch_bounds__(NTHR, 4) void fused_kernel(
    const float* __restrict__ X, const __bf16* __restrict__ wh,
    const __bf16* __restrict__ wl, const float* __restrict__ s1,
    const float* __restrict__ s2, const float* __restrict__ g2,
    const float* __restrict__ b2, float* __restrict__ out) {
  __shared__ LdsT lds;
  const int tid  = threadIdx.x;
  const int lane = tid & 63;
  const int wid  = tid >> 6;                 // 0..7
  const int row0 = blockIdx.x * BM;
  const int lrow = lane & 15, lgrp = lane >> 4;
  const int wr = wid >> 2, wc = wid & 3;     // wave tile: rows wr*32+32, cols wc*64+64
  const int srow = tid >> 3;                 // staging row 0..63
  const int sc4  = (tid & 7) * 4;            // staging col (fp32) within chunk
  const float* xbase = X + (size_t)(row0 + srow) * D_MODEL + sc4;

  // ---- prologue: chunk 0 in flight ----
#pragma unroll
  for (int call = 0; call < 2; ++call) {
    const int o = wid * 2048 + call * 1024 + lane * 16;
    gll16((const char*)wh + o, (char*)&lds.w[0][0] + wid * 2048 + call * 1024);
  }
  bf16x8 wlf0[4], wlf1[4];
#pragma unroll
  for (int n = 0; n < 4; ++n)
    wlf0[n] = *(const bf16x8*)(wl + (size_t)(wc * 64 + n * 16 + lrow) * D_MODEL + lgrp * 8);
  f32x4 xr = *(const f32x4*)xbase;

  f32x4 acc[2][4];
#pragma unroll
  for (int m = 0; m < 2; ++m)
#pragma unroll
    for (int n = 0; n < 4; ++n) acc[m][n] = (f32x4){0.f, 0.f, 0.f, 0.f};
  float ps = 0.f, pq = 0.f;

#define STEP(IT, P, WLF_CUR, WLF_NXT)                                              \
  {                                                                                \
    /* A: stats + hi/lo split + LDS stage (consumes xr -> drains prefetches) */    \
    union { __bf16 h[4]; uint64_t u; } ph_, pl_;                                   \
    _Pragma("unroll")                                                              \
    for (int j = 0; j < 4; ++j) {                                                  \
      float x = xr[j];                                                             \
      ps += x; pq += x * x;                                                        \
      __bf16 hb = (__bf16)x;                                                       \
      ph_.h[j] = hb;                                                               \
      pl_.h[j] = (__bf16)(x - (float)hb);                                          \
    }                                                                              \
    *(uint64_t*)&lds.xh[srow * XSTR + sc4] = ph_.u;                                \
    *(uint64_t*)&lds.xl[srow * XSTR + sc4] = pl_.u;                                \
    /* D: full barrier; vmcnt(0) drain is ~free (everything already consumed) */   \
    __syncthreads();                                                               \
    /* B': prefetch next chunk (stays in flight across F into next A) */           \
    if ((IT) + 1 < KITERS) {                                                       \
      _Pragma("unroll")                                                            \
      for (int call = 0; call < 2; ++call) {                                       \
        const int o = wid * 2048 + call * 1024 + lane * 16;                        \
        gll16((const char*)wh + (((size_t)(IT) + 1) << 14) + o,                    \
              (char*)&lds.w[(P) ^ 1][0] + wid * 2048 + call * 1024);               \
      }                                                                            \
      _Pragma("unroll")                                                            \
      for (int n = 0; n < 4; ++n)                                                  \
        WLF_NXT[n] = *(const bf16x8*)(wl +                                         \
            (size_t)(wc * 64 + n * 16 + lrow) * D_MODEL + ((IT) + 1) * BK + lgrp * 8); \
      xr = *(const f32x4*)(xbase + ((IT) + 1) * BK);                               \
    }                                                                              \
    /* E: fragments + 24 MFMA (3-split) */                                         \
    bf16x8 ah0 = *(const bf16x8*)&lds.xh[(wr * 32 +  0 + lrow) * XSTR + lgrp * 8]; \
    bf16x8 ah1 = *(const bf16x8*)&lds.xh[(wr * 32 + 16 + lrow) * XSTR + lgrp * 8]; \
    bf16x8 al0 = *(const bf16x8*)&lds.xl[(wr * 32 +  0 + lrow) * XSTR + lgrp * 8]; \
    bf16x8 al1 = *(const bf16x8*)&lds.xl[(wr * 32 + 16 + lrow) * XSTR + lgrp * 8]; \
    _Pragma("unroll")                                                              \
    for (int n = 0; n < 4; ++n) {                                                  \
      const int pp = wc * 64 + n * 16 + lrow;                                      \
      bf16x8 bh = *(const bf16x8*)&lds.w[P][pp * 32 + (lgrp ^ ((pp >> 1) & 3)) * 8]; \
      acc[0][n] = __builtin_amdgcn_mfma_f32_16x16x32_bf16(ah0, bh, acc[0][n], 0, 0, 0); \
      acc[1][n] = __builtin_amdgcn_mfma_f32_16x16x32_bf16(ah1, bh, acc[1][n], 0, 0, 0); \
      acc[0][n] = __builtin_amdgcn_mfma_f32_16x16x32_bf16(al0, bh, acc[0][n], 0, 0, 0); \
      acc[1][n] = __builtin_amdgcn_mfma_f32_16x16x32_bf16(al1, bh, acc[1][n], 0, 0, 0); \
      acc[0][n] = __builtin_amdgcn_mfma_f32_16x16x32_bf16(ah0, WLF_CUR[n], acc[0][n], 0, 0, 0); \
      acc[1][n] = __builtin_amdgcn_mfma_f32_16x16x32_bf16(ah1, WLF_CUR[n], acc[1][n], 0, 0, 0); \
    }                                                                              \
    /* F: raw barrier (keeps prefetches in flight); sched fences pin LDS order */  \
    __builtin_amdgcn_sched_barrier(0);                                             \
    __builtin_amdgcn_s_barrier();                                                  \
    __builtin_amdgcn_sched_barrier(0);                                             \
  }

  for (int it = 0; it < KITERS; it += 2) {
    STEP(it,     0, wlf0, wlf1);
    STEP(it + 1, 1, wlf1, wlf0);
  }
#undef STEP

  // ---- LN1 stats (8 lanes per row) ----
#pragma unroll
  for (int m = 1; m < 8; m <<= 1) {
    ps += __shfl_xor(ps, m, 64);
    pq += __shfl_xor(pq, m, 64);
  }
  if ((tid & 7) == 0) {
    float mu  = ps * (1.0f / D_MODEL);
    float var = pq * (1.0f / D_MODEL) - mu * mu;
    lds.mu[srow] = mu;
    lds.rs[srow] = rsqrtf(var + EPS);
  }
  __syncthreads();

  // ---- epilogue: LN1 affine correction, LN2 row stats, normalize, store ----
  float s1r[4], s2r[4], g2r[4], b2r[4];
#pragma unroll
  for (int n = 0; n < 4; ++n) {
    const int p = wc * 64 + n * 16 + lrow;
    s1r[n] = s1[p]; s2r[n] = s2[p];
    g2r[n] = g2[p]; b2r[n] = b2[p];
  }
#pragma unroll
  for (int m = 0; m < 2; ++m) {
#pragma unroll
    for (int j = 0; j < 4; ++j) {
      const int r = wr * 32 + m * 16 + lgrp * 4 + j;
      float muv = lds.mu[r], rsv = lds.rs[r];
      float rs_ = 0.f, rq_ = 0.f;
#pragma unroll
      for (int n = 0; n < 4; ++n) {
        float y = rsv * (acc[m][n][j] - muv * s1r[n]) + s2r[n];
        acc[m][n][j] = y;
        rs_ += y; rq_ += y * y;
      }
#pragma unroll
      for (int msk = 1; msk < 16; msk <<= 1) {
        rs_ += __shfl_xor(rs_, msk, 64);
        rq_ += __shfl_xor(rq_, msk, 64);
      }
      if (lrow == 0) { lds.red_s[wc][r] = rs_; lds.red_q[wc][r] = rq_; }
    }
  }
  __syncthreads();
#pragma unroll
  for (int m = 0; m < 2; ++m) {
#pragma unroll
    for (int j = 0; j < 4; ++j) {
      const int r = wr * 32 + m * 16 + lgrp * 4 + j;
      float S = lds.red_s[0][r] + lds.red_s[1][r] + lds.red_s[2][r] + lds.red_s[3][r];
      float Q = lds.red_q[0][r] + lds.red_q[1][r] + lds.red_q[2][r] + lds.red_q[3][r];
      float mu2  = S * (1.0f / D_PROJ);
      float var2 = Q * (1.0f / D_PROJ) - mu2 * mu2;
      float rs2  = rsqrtf(var2 + EPS);
      float* orow = out + (size_t)(row0 + r) * D_PROJ;
#pragma unroll
      for (int n = 0; n < 4; ++n)
        orow[wc * 64 + n * 16 + lrow] = (acc[m][n][j] - mu2) * rs2 * g2r[n] + b2r[n];
    }
  }
}

extern "C" void kernel_launch(void* const* d_in, const int* in_sizes, int n_in,
                              void* d_out, int out_size, void* d_ws, size_t ws_size,
                              hipStream_t stream) {
  const float* X  = (const float*)d_in[0];
  const float* g1 = (const float*)d_in[1];
  const float* b1 = (const float*)d_in[2];
  const float* W  = (const float*)d_in[3];
  const float* bb = (const float*)d_in[4];
  const float* g2 = (const float*)d_in[5];
  const float* b2 = (const float*)d_in[6];
  float* out = (float*)d_out;
  const int n_tok = in_sizes[0] / D_MODEL;

  __bf16* wh = (__bf16*)d_ws;                          // 512 KB swizzled chunk-major
  __bf16* wl = wh + (size_t)KITERS * 8192;             // 512 KB plain row-major
  float*  s1 = (float*)(wl + (size_t)D_PROJ * D_MODEL);
  float*  s2 = s1 + D_PROJ;

  prep_kernel<<<D_PROJ, 256, 0, stream>>>(W, g1, b1, bb, wh, wl, s1, s2);
  fused_kernel<<<n_tok / BM, NTHR, 0, stream>>>(X, wh, wl, s1, s2, g2, b2, out);
}